// Round 23
// baseline (177.226 us; speedup 1.0000x reference)
//
#include <hip/hip_runtime.h>
#include <hip/hip_bf16.h>

#define B_  4
#define T_  2048
#define C_  1024
#define H_  16
#define D_  64
#define BH_ (B_*H_)

typedef float  f32x4  __attribute__((ext_vector_type(4)));
typedef __bf16 bf16x8 __attribute__((ext_vector_type(8)));
typedef __bf16 bf16x2 __attribute__((ext_vector_type(2)));

static __device__ __forceinline__ ushort f2bf(float f) {
    union { float f; unsigned u; } x; x.f = f;
    unsigned r = ((x.u >> 16) & 1u) + 0x7fffu;
    return (ushort)((x.u + r) >> 16);
}

static __device__ __forceinline__ uint packbf(float a, float b) {
    bf16x2 v = { (__bf16)a, (__bf16)b };   // v_cvt_pk_bf16_f32
    return __builtin_bit_cast(uint, v);
}

static __device__ __forceinline__ void gload_lds16(const void* g, void* l) {
    __builtin_amdgcn_global_load_lds(
        (const __attribute__((address_space(1))) unsigned int*)g,
        (__attribute__((address_space(3))) unsigned int*)l, 16, 0, 0);
}

template<int N> static __device__ __forceinline__ void waitcnt_vm() {
    if constexpr (N == 0) asm volatile("s_waitcnt vmcnt(0)" ::: "memory");
    else if constexpr (N == 4) asm volatile("s_waitcnt vmcnt(4)" ::: "memory");
    else if constexpr (N == 6) asm volatile("s_waitcnt vmcnt(6)" ::: "memory");
    else static_assert(N == 0 || N == 4 || N == 6);
    __builtin_amdgcn_sched_barrier(0);
}

// ---------------- fused prep: x->bf16 + both weight transposes ----------------
__global__ __launch_bounds__(256) void prep_kernel(
    const float* __restrict__ x,     ushort* __restrict__ xb,
    const float* __restrict__ wqkv,  ushort* __restrict__ wqkvT,
    const float* __restrict__ wout,  ushort* __restrict__ woutT)
{
    __shared__ float tile[32][33];
    const int bid = blockIdx.x;
    if (bid < 8192) {
        int i = (bid * 256 + threadIdx.x) * 4;
        float4 v = *(const float4*)(x + i);
        ushort4 o;
        o.x = f2bf(v.x); o.y = f2bf(v.y); o.z = f2bf(v.z); o.w = f2bf(v.w);
        *(ushort4*)(xb + i) = o;
        return;
    }
    const float* in; ushort* out; int K, N, t;
    if (bid < 8192 + 3072) { t = bid - 8192;        in = wqkv; out = wqkvT; K = 1024; N = 3072; }
    else                   { t = bid - 8192 - 3072; in = wout; out = woutT; K = 1024; N = 1024; }
    const int nbx = N / 32;
    const int n0 = (t % nbx) * 32, k0 = (t / nbx) * 32;
    const int tx = threadIdx.x & 31, ty = threadIdx.x >> 5;  // 32 x 8
    #pragma unroll
    for (int r = 0; r < 32; r += 8)
        tile[ty + r][tx] = in[(size_t)(k0 + ty + r) * N + n0 + tx];
    __syncthreads();
    #pragma unroll
    for (int r = 0; r < 32; r += 8)
        out[(size_t)(n0 + ty + r) * K + k0 + tx] = f2bf(tile[tx][ty + r]);
}

// ---------------- GEMM v4 (R21/R22 verbatim): conflict-free full-row LDS + persistent-n ----------------
template<int MFR, int NFR, int NG, bool QKV>
__global__ __launch_bounds__(512, 2) void gemm_hk(
    const ushort* __restrict__ A,    // M x 1024 bf16 (row-major)
    const ushort* __restrict__ Bt,   // N x 1024 bf16 (N x K)
    const float*  __restrict__ bias,
    void* __restrict__ outp,
    ushort* __restrict__ vtp)        // vT base (QKV only)
{
    constexpr int NT    = 16;              // K=1024 / BK=64
    constexpr int BM    = MFR * 32;
    constexpr int BN    = NFR * 64;
    constexpr int APASS = BM / 64;         // staging passes (64 rows x 8KB each)
    constexpr int BPASS = BN / 64;
    constexpr int ABUF  = BM * 128;        // bytes per A buffer (full 128B rows)
    constexpr int BBUF  = BN * 128;
    __shared__ __align__(16) char lds[2 * ABUF + 2 * BBUF];
    char* ldsB = lds + 2 * ABUF;

    // XCD-chunked swizzle (bijective: nwg % 8 == 0)
    const int gX   = gridDim.x;
    const int orig = blockIdx.y * gX + blockIdx.x;
    const int cpx  = (gX * gridDim.y) >> 3;
    const int wg   = (orig & 7) * cpx + (orig >> 3);
    const int m0 = (wg / gX) * BM, n0 = (wg % gX) * BN;

    const int tid = threadIdx.x, lane = tid & 63;
    const int wv = tid >> 6, wm = wv >> 2, wn = wv & 3;
    const int lr = lane & 15, lh = lane >> 4;

    // staging: thread -> row (tid>>3) (+p*64), stored chunk tid&7 (linear dest);
    // source data chunk = (tid&7) ^ (row&7)  [involution]
    const int dchunk = (tid & 7) ^ ((tid >> 3) & 7);
    const ushort* aA = A + (size_t)(m0 + (tid >> 3)) * 1024 + dchunk * 8;

    // read-side: fragment rows have row&7 == lr&7; data chunk kh*4+lh
    const int axor0 = ((0 + lh) ^ (lr & 7)) * 16;   // kh = 0
    const int axor1 = ((4 + lh) ^ (lr & 7)) * 16;   // kh = 1

    #pragma unroll 1
    for (int g = 0; g < NG; ++g) {
        const int n0g = n0 + g * (gX * BN);
        const ushort* aB = Bt + (size_t)(n0g + (tid >> 3)) * 1024 + dchunk * 8;

        f32x4 acc[MFR][NFR] = {};

        auto stage = [&](int buf, int t) {
            #pragma unroll
            for (int p = 0; p < APASS; ++p)
                gload_lds16(aA + (size_t)p * 65536 + t * 64,
                            lds + buf * ABUF + p * 8192 + tid * 16);
            #pragma unroll
            for (int p = 0; p < BPASS; ++p)
                gload_lds16(aB + (size_t)p * 65536 + t * 64,
                            ldsB + buf * BBUF + p * 8192 + tid * 16);
        };
        auto read_a = [&](bf16x8 (&af)[MFR], int buf, int kh) {
            const char* base = lds + buf * ABUF + (wm * (MFR * 16) + lr) * 128
                                   + (kh ? axor1 : axor0);
            #pragma unroll
            for (int mi = 0; mi < MFR; ++mi) af[mi] = *(const bf16x8*)(base + mi * 2048);
        };
        auto read_b = [&](bf16x8& b0, bf16x8& b1, int buf, int kh) {
            const char* base = ldsB + buf * BBUF + (wn * (NFR * 16) + lr) * 128
                                    + (kh ? axor1 : axor0);
            b0 = *(const bf16x8*)(base);
            b1 = *(const bf16x8*)(base + 2048);
        };

#define MFMA2(BB0, BB1)                                                              \
        do {                                                                         \
            __builtin_amdgcn_s_setprio(1);                                           \
            _Pragma("unroll")                                                        \
            for (int mi = 0; mi < MFR; ++mi) {                                       \
                acc[mi][0] = __builtin_amdgcn_mfma_f32_16x16x32_bf16(af[mi], BB0,    \
                                                         acc[mi][0], 0, 0, 0);       \
                acc[mi][1] = __builtin_amdgcn_mfma_f32_16x16x32_bf16(af[mi], BB1,    \
                                                         acc[mi][1], 0, 0, 0);       \
            }                                                                        \
            __builtin_amdgcn_s_setprio(0);                                           \
        } while (0)

        // prologue: stage tiles 0 and 1 (6 loads each); at g>0 the vmcnt(6)
        // below additionally drains the previous epilogue's stores (correct).
        stage(0, 0);
        stage(1, 1);

        for (int t = 0; t < NT; ++t) {
            const int cur = t & 1;
            if (t < NT - 1) waitcnt_vm<6>();   // tile t landed (t+1's 6 may fly)
            else            waitcnt_vm<0>();
            __builtin_amdgcn_s_barrier();      // globally visible

            bf16x8 af[MFR], b0, b1;
            read_a(af, cur, 0); read_b(b0, b1, cur, 0);
            MFMA2(b0, b1);                     // compiler inserts lgkmcnt
            read_a(af, cur, 1); read_b(b0, b1, cur, 1);
            MFMA2(b0, b1);

            __builtin_amdgcn_s_barrier();      // all waves done reading cur
            if (t + 2 < NT) stage(cur, t + 2); // overwrite cur with tile t+2
        }
#undef MFMA2

        #pragma unroll
        for (int mi = 0; mi < MFR; ++mi) {
            #pragma unroll
            for (int ni = 0; ni < NFR; ++ni) {
                int col = n0g + wn * (NFR * 16) + ni * 16 + lr;
                float bv = bias[col];
                if constexpr (QKV) {
                    ushort* qkv = (ushort*)outp;
                    const int which = g;         // n-groups spaced 1024 cols
                    int h = (col & 1023) >> 6;
                    int d = col & 63;
                    if (which == 2) {
                        // V: write directly transposed -> vT[(bh*64+d)*T + t]
                        #pragma unroll
                        for (int r = 0; r < 4; ++r) {
                            int row = m0 + wm * (MFR * 16) + mi * 16 + lh * 4 + r;
                            int b = row >> 11, tt = row & 2047;
                            vtp[(((size_t)(b * H_ + h)) * D_ + d) * T_ + tt] =
                                f2bf(acc[mi][ni][r] + bv);
                        }
                    } else {
                        #pragma unroll
                        for (int r = 0; r < 4; ++r) {
                            int row = m0 + wm * (MFR * 16) + mi * 16 + lh * 4 + r;
                            int b = row >> 11, tt = row & 2047;
                            float v = acc[mi][ni][r] + bv;
                            if (which == 0) v *= 0.18033688011112042f;  // 1/8*log2(e)
                            qkv[(size_t)which * (BH_ * T_ * D_) +
                                (((size_t)(b * H_ + h)) * T_ + tt) * D_ + d] = f2bf(v);
                        }
                    }
                } else {
                    float* Cout = (float*)outp;
                    #pragma unroll
                    for (int r = 0; r < 4; ++r) {
                        int row = m0 + wm * (MFR * 16) + mi * 16 + lh * 4 + r;
                        Cout[(size_t)row * C_ + col] = acc[mi][ni][r] + bv;
                    }
                }
            }
        }
    }
}

// ---------------- flash attention v12: counted-vmcnt barriers (no end-of-tile drain) ----------------
// R22 body with __syncthreads() replaced by raw s_barrier + counted vmcnt(4):
// kt+1's 4 staging loads stay in flight across the compute AND the barrier
// (T4). WAR safe: buffer nb overwritten at top of kt was last read in kt-1,
// whose trailing barrier precedes. No VALU LDS writes exist (in-register P).
// (256,4) cap is LOAD-BEARING: forces 64-VGPR -> 4 blocks/CU (R21: without it
// 92 VGPR -> 18% occ -> 103us).
__global__ __launch_bounds__(256, 4) void flash_kernel(
    const ushort* __restrict__ qb,  // (bh, t, d) bf16, pre-scaled
    const ushort* __restrict__ kb,  // (bh, t, d) bf16
    const ushort* __restrict__ vt,  // (bh, d, t) bf16
    ushort* __restrict__ ob)        // (b*t, 1024) bf16
{
    __shared__ __align__(16) ushort sK[2][64 * 64];
    __shared__ __align__(16) ushort sV[2][64 * 64];
    const int wg  = ((blockIdx.x & 7) << 7) | (blockIdx.x >> 3);  // 1024 blocks
    const int bh  = wg >> 4;
    const int pr  = wg & 15;
    const int qtA = pr, qtB = 31 - pr;
    const int lane = threadIdx.x & 63, wv = threadIdx.x >> 6;
    const int lr = lane & 15, lh = lane >> 4;

    const ushort* qrowA = qb + ((size_t)bh * T_ + qtA * 64 + wv * 16 + lr) * D_;
    const ushort* qrowB = qb + ((size_t)bh * T_ + qtB * 64 + wv * 16 + lr) * D_;
    bf16x8 qfA0 = *(const bf16x8*)(qrowA + lh * 8);
    bf16x8 qfA1 = *(const bf16x8*)(qrowA + 32 + lh * 8);
    bf16x8 qfB0 = *(const bf16x8*)(qrowB + lh * 8);
    bf16x8 qfB1 = *(const bf16x8*)(qrowB + 32 + lh * 8);

    const int srow = lane >> 3;
    const int scol = ((lane & 7) ^ srow) * 8;
    const ushort* kbase = kb + (size_t)bh * T_ * D_;
    const ushort* vbase = vt + (size_t)bh * D_ * T_;

    const int swv  = (lr & 7) << 4;           // V-read swizzle (rows == lr mod 8)
    const int off0 = (16 * lh) ^ swv;
    const int off1 = (64 + 16 * lh) ^ swv;

    f32x4 oA[4] = {}, oB[4] = {};
    float mA = -1e30f, lA = 0.f, mB = -1e30f, lB = 0.f;   // lA/lB: per-lane partials

    auto redmax = [&](float x) {
        x = fmaxf(x, __int_as_float(__builtin_amdgcn_ds_swizzle(__float_as_int(x), 0x401F)));
        x = fmaxf(x, __shfl_xor(x, 32, 64));
        return x;
    };
    auto redsum = [&](float x) {
        x += __int_as_float(__builtin_amdgcn_ds_swizzle(__float_as_int(x), 0x401F));
        x += __shfl_xor(x, 32, 64);
        return x;
    };

    auto maskS = [&](f32x4 (&s)[4]) {   // causal, permuted k mapping
        #pragma unroll
        for (int nt = 0; nt < 4; ++nt) {
            const int kb0 = 8 * lh + 4 * (nt & 1) + 32 * (nt >> 1);
            #pragma unroll
            for (int r = 0; r < 4; ++r)
                if (kb0 + r > wv * 16 + lr) s[nt][r] = -INFINITY;
        }
    };

    auto softmax_pv = [&](f32x4 (&s)[4], float& mrow, float& lsum, f32x4 (&o)[4],
                          const char* V0) {
        float t0 = fmaxf(fmaxf(s[0][0], s[0][1]), s[0][2]);
        float t1 = fmaxf(fmaxf(s[0][3], s[1][0]), s[1][1]);
        float t2 = fmaxf(fmaxf(s[1][2], s[1][3]), s[2][0]);
        float t3 = fmaxf(fmaxf(s[2][1], s[2][2]), s[2][3]);
        float t4 = fmaxf(fmaxf(s[3][0], s[3][1]), s[3][2]);
        float u0 = fmaxf(fmaxf(t0, t1), t2);
        float u1 = fmaxf(fmaxf(t3, t4), s[3][3]);
        float lmax = fmaxf(u0, u1);
        // defer-max (T13): wave-level predicate, no cross-lane reduce on hot path
        if (__any(lmax > mrow + 8.f)) {
            float pmax = redmax(lmax);          // uniform within lr-group
            float mnew = fmaxf(mrow, pmax);
            float al = __builtin_exp2f(mrow - mnew);
            lsum *= al;                          // per-lane partial, uniform scale
            #pragma unroll
            for (int r = 0; r < 4; ++r) {
                float ar = __shfl(al, lh * 20 + r, 64);
                o[0][r] *= ar; o[1][r] *= ar; o[2][r] *= ar; o[3][r] *= ar;
            }
            mrow = mnew;
        }
        float rsum = 0.f;
        uint pk[8];
        #pragma unroll
        for (int nt = 0; nt < 4; ++nt) {
            float p0 = __builtin_exp2f(s[nt][0] - mrow);
            float p1 = __builtin_exp2f(s[nt][1] - mrow);
            float p2 = __builtin_exp2f(s[nt][2] - mrow);
            float p3 = __builtin_exp2f(s[nt][3] - mrow);
            rsum += (p0 + p1) + (p2 + p3);
            pk[nt * 2]     = packbf(p0, p1);
            pk[nt * 2 + 1] = packbf(p2, p3);
        }
        lsum += rsum;                            // NO cross-lane reduce here
        uint4 w0 = {pk[0], pk[1], pk[2], pk[3]};
        uint4 w1 = {pk[4], pk[5], pk[6], pk[7]};
        bf16x8 pf0 = __builtin_bit_cast(bf16x8, w0);
        bf16x8 pf1 = __builtin_bit_cast(bf16x8, w1);
        __builtin_amdgcn_s_setprio(1);
        #pragma unroll
        for (int dt = 0; dt < 4; ++dt) {
            const char* vrow = V0 + (dt * 16 + lr) * 128;
            bf16x8 v0 = *(const bf16x8*)(vrow + off0);
            bf16x8 v1 = *(const bf16x8*)(vrow + off1);
            o[dt] = __builtin_amdgcn_mfma_f32_16x16x32_bf16(pf0, v0, o[dt], 0, 0, 0);
            o[dt] = __builtin_amdgcn_mfma_f32_16x16x32_bf16(pf1, v1, o[dt], 0, 0, 0);
        }
        __builtin_amdgcn_s_setprio(0);
    };

    // prologue: stage tile 0 (4 loads/wave); landing enforced at loop top
    #pragma unroll
    for (int i = 0; i < 2; ++i) {
        int j = i * 4 + wv;
        gload_lds16(kbase + (size_t)(j * 8 + srow) * D_ + scol, &sK[0][j * 512]);
        gload_lds16(vbase + (size_t)(j * 8 + srow) * T_ + scol, &sV[0][j * 512]);
    }

    for (int kt = 0; kt <= qtB; ++kt) {
        const int cur = kt & 1;
        if (kt < qtB) {
            const int nb = cur ^ 1;   // last read in kt-1; trailing barrier passed
            #pragma unroll
            for (int i = 0; i < 2; ++i) {
                int j = i * 4 + wv;
                gload_lds16(kbase + (size_t)((kt + 1) * 64 + j * 8 + srow) * D_ + scol, &sK[nb][j * 512]);
                gload_lds16(vbase + (size_t)(j * 8 + srow) * T_ + (kt + 1) * 64 + scol, &sV[nb][j * 512]);
            }
            waitcnt_vm<4>();          // tile kt's 4 landed; kt+1's 4 stay in flight
        } else {
            waitcnt_vm<0>();
        }
        __builtin_amdgcn_s_barrier(); // all waves: tile kt visible

        const bool doA = kt <= qtA;
        const char* K0 = (const char*)sK[cur];
        const char* V0 = (const char*)sV[cur];

        f32x4 sa[4], sb[4];
        __builtin_amdgcn_s_setprio(1);
        #pragma unroll
        for (int nt = 0; nt < 4; ++nt) {
            const int kk  = ((lr >> 2) << 3) | (lr & 3) | ((nt & 1) << 2) | ((nt >> 1) << 5);
            const int swk = (kk & 7) << 4;
            const char* krow = K0 + kk * 128;
            bf16x8 k0 = *(const bf16x8*)(krow + ((16 * lh) ^ swk));
            bf16x8 k1 = *(const bf16x8*)(krow + ((64 + 16 * lh) ^ swk));
            f32x4 a = {0.f, 0.f, 0.f, 0.f};
            a = __builtin_amdgcn_mfma_f32_16x16x32_bf16(k0, qfB0, a, 0, 0, 0);
            a = __builtin_amdgcn_mfma_f32_16x16x32_bf16(k1, qfB1, a, 0, 0, 0);
            sb[nt] = a;
            if (doA) {
                f32x4 c = {0.f, 0.f, 0.f, 0.f};
                c = __builtin_amdgcn_mfma_f32_16x16x32_bf16(k0, qfA0, c, 0, 0, 0);
                c = __builtin_amdgcn_mfma_f32_16x16x32_bf16(k1, qfA1, c, 0, 0, 0);
                sa[nt] = c;
            }
        }
        __builtin_amdgcn_s_setprio(0);
        if (kt == qtB) maskS(sb);
        if (doA && kt == qtA) maskS(sa);

        softmax_pv(sb, mB, lB, oB, V0);
        if (doA) softmax_pv(sa, mA, lA, oA, V0);

        __builtin_amdgcn_s_barrier(); // all waves done reading cur
    }

    const int b = bh >> 4, h = bh & 15;
    auto writeout = [&](f32x4 (&o)[4], float lsum, int q0) {
        float inv = 1.f / redsum(lsum);          // single deferred cross-lane reduce
        #pragma unroll
        for (int r = 0; r < 4; ++r) {
            float ir = __shfl(inv, lh * 20 + r, 64);
            int q = q0 + lh * 4 + r;
            #pragma unroll
            for (int dt = 0; dt < 4; ++dt)
                ob[((size_t)b * T_ + q) * C_ + h * 64 + dt * 16 + lr] = f2bf(o[dt][r] * ir);
        }
    };
    writeout(oA, lA, qtA * 64 + wv * 16);
    writeout(oB, lB, qtB * 64 + wv * 16);
}

extern "C" void kernel_launch(void* const* d_in, const int* in_sizes, int n_in,
                              void* d_out, int out_size, void* d_ws, size_t ws_size,
                              hipStream_t stream) {
    const float* x     = (const float*)d_in[0];
    const float* w_qkv = (const float*)d_in[1];
    const float* b_qkv = (const float*)d_in[2];
    const float* w_out = (const float*)d_in[3];
    const float* b_out = (const float*)d_in[4];
    float* out = (float*)d_out;

    char* ws = (char*)d_ws;
    ushort* xb     = (ushort*)(ws + 0);           // 16 MB (aliased: attn out reuses after GEMM1)
    ushort* wqkvT  = (ushort*)(ws + 16777216);    // 6 MB
    ushort* woutT  = (ushort*)(ws + 23068672);    // 2 MB
    ushort* qkv    = (ushort*)(ws + 25165824);    // q,k (bh,t,d); v-third unused
    ushort* vT     = (ushort*)(ws + 75497472);    // 16 MB (bh,d,t), written by gemm_hk qkv
    ushort* attn   = xb;
    ushort* qb = qkv;
    ushort* kb = qkv + (size_t)BH_ * T_ * D_;

    prep_kernel<<<8192 + 3072 + 1024, 256, 0, stream>>>(x, xb, w_qkv, wqkvT, w_out, woutT);
    // persistent-n qkv: 8 x 32 = 256 blocks = exactly 1.0 dispatch wave, NG=3
    gemm_hk<8, 2, 3, true><<<dim3(8, B_ * T_ / 256), 512, 0, stream>>>(xb, wqkvT, b_qkv, qkv, vT);
    flash_kernel<<<BH_ * 16, 256, 0, stream>>>(qb, kb, vT, attn);
    // BM=256, BN=128: 8 x 32 = 256 blocks = exactly 1.0 wave, NG=1
    gemm_hk<8, 2, 1, false><<<dim3(C_ / 128, B_ * T_ / 256), 512, 0, stream>>>(attn, woutT, b_out, out, nullptr);
}

// Round 24
// 174.631 us; speedup vs baseline: 1.0149x; 1.0149x over previous
//
#include <hip/hip_runtime.h>
#include <hip/hip_bf16.h>

#define B_  4
#define T_  2048
#define C_  1024
#define H_  16
#define D_  64
#define BH_ (B_*H_)

typedef float  f32x4  __attribute__((ext_vector_type(4)));
typedef __bf16 bf16x8 __attribute__((ext_vector_type(8)));
typedef __bf16 bf16x2 __attribute__((ext_vector_type(2)));

static __device__ __forceinline__ ushort f2bf(float f) {
    union { float f; unsigned u; } x; x.f = f;
    unsigned r = ((x.u >> 16) & 1u) + 0x7fffu;
    return (ushort)((x.u + r) >> 16);
}

static __device__ __forceinline__ uint packbf(float a, float b) {
    bf16x2 v = { (__bf16)a, (__bf16)b };   // v_cvt_pk_bf16_f32
    return __builtin_bit_cast(uint, v);
}

static __device__ __forceinline__ void gload_lds16(const void* g, void* l) {
    __builtin_amdgcn_global_load_lds(
        (const __attribute__((address_space(1))) unsigned int*)g,
        (__attribute__((address_space(3))) unsigned int*)l, 16, 0, 0);
}

template<int N> static __device__ __forceinline__ void waitcnt_vm() {
    if constexpr (N == 0) asm volatile("s_waitcnt vmcnt(0)" ::: "memory");
    else if constexpr (N == 6) asm volatile("s_waitcnt vmcnt(6)" ::: "memory");
    else static_assert(N == 0 || N == 6);
    __builtin_amdgcn_sched_barrier(0);
}

// ---------------- fused prep: x->bf16 + both weight transposes ----------------
__global__ __launch_bounds__(256) void prep_kernel(
    const float* __restrict__ x,     ushort* __restrict__ xb,
    const float* __restrict__ wqkv,  ushort* __restrict__ wqkvT,
    const float* __restrict__ wout,  ushort* __restrict__ woutT)
{
    __shared__ float tile[32][33];
    const int bid = blockIdx.x;
    if (bid < 8192) {
        int i = (bid * 256 + threadIdx.x) * 4;
        float4 v = *(const float4*)(x + i);
        ushort4 o;
        o.x = f2bf(v.x); o.y = f2bf(v.y); o.z = f2bf(v.z); o.w = f2bf(v.w);
        *(ushort4*)(xb + i) = o;
        return;
    }
    const float* in; ushort* out; int K, N, t;
    if (bid < 8192 + 3072) { t = bid - 8192;        in = wqkv; out = wqkvT; K = 1024; N = 3072; }
    else                   { t = bid - 8192 - 3072; in = wout; out = woutT; K = 1024; N = 1024; }
    const int nbx = N / 32;
    const int n0 = (t % nbx) * 32, k0 = (t / nbx) * 32;
    const int tx = threadIdx.x & 31, ty = threadIdx.x >> 5;  // 32 x 8
    #pragma unroll
    for (int r = 0; r < 32; r += 8)
        tile[ty + r][tx] = in[(size_t)(k0 + ty + r) * N + n0 + tx];
    __syncthreads();
    #pragma unroll
    for (int r = 0; r < 32; r += 8)
        out[(size_t)(n0 + ty + r) * K + k0 + tx] = f2bf(tile[tx][ty + r]);
}

// ---------------- GEMM v4 (R22 verbatim): conflict-free full-row LDS + persistent-n ----------------
template<int MFR, int NFR, int NG, bool QKV>
__global__ __launch_bounds__(512, 2) void gemm_hk(
    const ushort* __restrict__ A,    // M x 1024 bf16 (row-major)
    const ushort* __restrict__ Bt,   // N x 1024 bf16 (N x K)
    const float*  __restrict__ bias,
    void* __restrict__ outp,
    ushort* __restrict__ vtp)        // vT base (QKV only)
{
    constexpr int NT    = 16;              // K=1024 / BK=64
    constexpr int BM    = MFR * 32;
    constexpr int BN    = NFR * 64;
    constexpr int APASS = BM / 64;         // staging passes (64 rows x 8KB each)
    constexpr int BPASS = BN / 64;
    constexpr int ABUF  = BM * 128;        // bytes per A buffer (full 128B rows)
    constexpr int BBUF  = BN * 128;
    __shared__ __align__(16) char lds[2 * ABUF + 2 * BBUF];
    char* ldsB = lds + 2 * ABUF;

    // XCD-chunked swizzle (bijective: nwg % 8 == 0)
    const int gX   = gridDim.x;
    const int orig = blockIdx.y * gX + blockIdx.x;
    const int cpx  = (gX * gridDim.y) >> 3;
    const int wg   = (orig & 7) * cpx + (orig >> 3);
    const int m0 = (wg / gX) * BM, n0 = (wg % gX) * BN;

    const int tid = threadIdx.x, lane = tid & 63;
    const int wv = tid >> 6, wm = wv >> 2, wn = wv & 3;
    const int lr = lane & 15, lh = lane >> 4;

    // staging: thread -> row (tid>>3) (+p*64), stored chunk tid&7 (linear dest);
    // source data chunk = (tid&7) ^ (row&7)  [involution]
    const int dchunk = (tid & 7) ^ ((tid >> 3) & 7);
    const ushort* aA = A + (size_t)(m0 + (tid >> 3)) * 1024 + dchunk * 8;

    // read-side: fragment rows have row&7 == lr&7; data chunk kh*4+lh
    const int axor0 = ((0 + lh) ^ (lr & 7)) * 16;   // kh = 0
    const int axor1 = ((4 + lh) ^ (lr & 7)) * 16;   // kh = 1

    #pragma unroll 1
    for (int g = 0; g < NG; ++g) {
        const int n0g = n0 + g * (gX * BN);
        const ushort* aB = Bt + (size_t)(n0g + (tid >> 3)) * 1024 + dchunk * 8;

        f32x4 acc[MFR][NFR] = {};

        auto stage = [&](int buf, int t) {
            #pragma unroll
            for (int p = 0; p < APASS; ++p)
                gload_lds16(aA + (size_t)p * 65536 + t * 64,
                            lds + buf * ABUF + p * 8192 + tid * 16);
            #pragma unroll
            for (int p = 0; p < BPASS; ++p)
                gload_lds16(aB + (size_t)p * 65536 + t * 64,
                            ldsB + buf * BBUF + p * 8192 + tid * 16);
        };
        auto read_a = [&](bf16x8 (&af)[MFR], int buf, int kh) {
            const char* base = lds + buf * ABUF + (wm * (MFR * 16) + lr) * 128
                                   + (kh ? axor1 : axor0);
            #pragma unroll
            for (int mi = 0; mi < MFR; ++mi) af[mi] = *(const bf16x8*)(base + mi * 2048);
        };
        auto read_b = [&](bf16x8& b0, bf16x8& b1, int buf, int kh) {
            const char* base = ldsB + buf * BBUF + (wn * (NFR * 16) + lr) * 128
                                    + (kh ? axor1 : axor0);
            b0 = *(const bf16x8*)(base);
            b1 = *(const bf16x8*)(base + 2048);
        };

#define MFMA2(BB0, BB1)                                                              \
        do {                                                                         \
            __builtin_amdgcn_s_setprio(1);                                           \
            _Pragma("unroll")                                                        \
            for (int mi = 0; mi < MFR; ++mi) {                                       \
                acc[mi][0] = __builtin_amdgcn_mfma_f32_16x16x32_bf16(af[mi], BB0,    \
                                                         acc[mi][0], 0, 0, 0);       \
                acc[mi][1] = __builtin_amdgcn_mfma_f32_16x16x32_bf16(af[mi], BB1,    \
                                                         acc[mi][1], 0, 0, 0);       \
            }                                                                        \
            __builtin_amdgcn_s_setprio(0);                                           \
        } while (0)

        // prologue: stage tiles 0 and 1 (6 loads each); at g>0 the vmcnt(6)
        // below additionally drains the previous epilogue's stores (correct).
        stage(0, 0);
        stage(1, 1);

        for (int t = 0; t < NT; ++t) {
            const int cur = t & 1;
            if (t < NT - 1) waitcnt_vm<6>();   // tile t landed (t+1's 6 may fly)
            else            waitcnt_vm<0>();
            __builtin_amdgcn_s_barrier();      // globally visible

            bf16x8 af[MFR], b0, b1;
            read_a(af, cur, 0); read_b(b0, b1, cur, 0);
            MFMA2(b0, b1);                     // compiler inserts lgkmcnt
            read_a(af, cur, 1); read_b(b0, b1, cur, 1);
            MFMA2(b0, b1);

            __builtin_amdgcn_s_barrier();      // all waves done reading cur
            if (t + 2 < NT) stage(cur, t + 2); // overwrite cur with tile t+2
        }
#undef MFMA2

        #pragma unroll
        for (int mi = 0; mi < MFR; ++mi) {
            #pragma unroll
            for (int ni = 0; ni < NFR; ++ni) {
                int col = n0g + wn * (NFR * 16) + ni * 16 + lr;
                float bv = bias[col];
                if constexpr (QKV) {
                    ushort* qkv = (ushort*)outp;
                    const int which = g;         // n-groups spaced 1024 cols
                    int h = (col & 1023) >> 6;
                    int d = col & 63;
                    if (which == 2) {
                        // V: write directly transposed -> vT[(bh*64+d)*T + t]
                        #pragma unroll
                        for (int r = 0; r < 4; ++r) {
                            int row = m0 + wm * (MFR * 16) + mi * 16 + lh * 4 + r;
                            int b = row >> 11, tt = row & 2047;
                            vtp[(((size_t)(b * H_ + h)) * D_ + d) * T_ + tt] =
                                f2bf(acc[mi][ni][r] + bv);
                        }
                    } else {
                        #pragma unroll
                        for (int r = 0; r < 4; ++r) {
                            int row = m0 + wm * (MFR * 16) + mi * 16 + lh * 4 + r;
                            int b = row >> 11, tt = row & 2047;
                            float v = acc[mi][ni][r] + bv;
                            if (which == 0) v *= 0.18033688011112042f;  // 1/8*log2(e)
                            qkv[(size_t)which * (BH_ * T_ * D_) +
                                (((size_t)(b * H_ + h)) * T_ + tt) * D_ + d] = f2bf(v);
                        }
                    }
                } else {
                    float* Cout = (float*)outp;
                    #pragma unroll
                    for (int r = 0; r < 4; ++r) {
                        int row = m0 + wm * (MFR * 16) + mi * 16 + lh * 4 + r;
                        Cout[(size_t)row * C_ + col] = acc[mi][ni][r] + bv;
                    }
                }
            }
        }
    }
}

// ---------------- flash attention v10 (R22 verbatim): __launch_bounds__(256,4) ----------------
// (256,4) cap is LOAD-BEARING: forces 64-VGPR -> 4 blocks/CU (R21: without it
// 92 VGPR -> 18% occ -> 103us). __syncthreads per tile (counted-vmcnt variant
// was neutral-to-negative: R23). ONE softmax-state live at a time (two live
// P-fragment sets spill: R7, R18).
__global__ __launch_bounds__(256, 4) void flash_kernel(
    const ushort* __restrict__ qb,  // (bh, t, d) bf16, pre-scaled
    const ushort* __restrict__ kb,  // (bh, t, d) bf16
    const ushort* __restrict__ vt,  // (bh, d, t) bf16
    ushort* __restrict__ ob)        // (b*t, 1024) bf16
{
    __shared__ __align__(16) ushort sK[2][64 * 64];
    __shared__ __align__(16) ushort sV[2][64 * 64];
    const int wg  = ((blockIdx.x & 7) << 7) | (blockIdx.x >> 3);  // 1024 blocks
    const int bh  = wg >> 4;
    const int pr  = wg & 15;
    const int qtA = pr, qtB = 31 - pr;
    const int lane = threadIdx.x & 63, wv = threadIdx.x >> 6;
    const int lr = lane & 15, lh = lane >> 4;

    const ushort* qrowA = qb + ((size_t)bh * T_ + qtA * 64 + wv * 16 + lr) * D_;
    const ushort* qrowB = qb + ((size_t)bh * T_ + qtB * 64 + wv * 16 + lr) * D_;
    bf16x8 qfA0 = *(const bf16x8*)(qrowA + lh * 8);
    bf16x8 qfA1 = *(const bf16x8*)(qrowA + 32 + lh * 8);
    bf16x8 qfB0 = *(const bf16x8*)(qrowB + lh * 8);
    bf16x8 qfB1 = *(const bf16x8*)(qrowB + 32 + lh * 8);

    const int srow = lane >> 3;
    const int scol = ((lane & 7) ^ srow) * 8;
    const ushort* kbase = kb + (size_t)bh * T_ * D_;
    const ushort* vbase = vt + (size_t)bh * D_ * T_;

    const int swv  = (lr & 7) << 4;           // V-read swizzle (rows == lr mod 8)
    const int off0 = (16 * lh) ^ swv;
    const int off1 = (64 + 16 * lh) ^ swv;

    f32x4 oA[4] = {}, oB[4] = {};
    float mA = -1e30f, lA = 0.f, mB = -1e30f, lB = 0.f;   // lA/lB: per-lane partials

    auto redmax = [&](float x) {
        x = fmaxf(x, __int_as_float(__builtin_amdgcn_ds_swizzle(__float_as_int(x), 0x401F)));
        x = fmaxf(x, __shfl_xor(x, 32, 64));
        return x;
    };
    auto redsum = [&](float x) {
        x += __int_as_float(__builtin_amdgcn_ds_swizzle(__float_as_int(x), 0x401F));
        x += __shfl_xor(x, 32, 64);
        return x;
    };

    auto maskS = [&](f32x4 (&s)[4]) {   // causal, permuted k mapping
        #pragma unroll
        for (int nt = 0; nt < 4; ++nt) {
            const int kb0 = 8 * lh + 4 * (nt & 1) + 32 * (nt >> 1);
            #pragma unroll
            for (int r = 0; r < 4; ++r)
                if (kb0 + r > wv * 16 + lr) s[nt][r] = -INFINITY;
        }
    };

    auto softmax_pv = [&](f32x4 (&s)[4], float& mrow, float& lsum, f32x4 (&o)[4],
                          const char* V0) {
        float t0 = fmaxf(fmaxf(s[0][0], s[0][1]), s[0][2]);
        float t1 = fmaxf(fmaxf(s[0][3], s[1][0]), s[1][1]);
        float t2 = fmaxf(fmaxf(s[1][2], s[1][3]), s[2][0]);
        float t3 = fmaxf(fmaxf(s[2][1], s[2][2]), s[2][3]);
        float t4 = fmaxf(fmaxf(s[3][0], s[3][1]), s[3][2]);
        float u0 = fmaxf(fmaxf(t0, t1), t2);
        float u1 = fmaxf(fmaxf(t3, t4), s[3][3]);
        float lmax = fmaxf(u0, u1);
        // defer-max (T13): wave-level predicate, no cross-lane reduce on hot path
        if (__any(lmax > mrow + 8.f)) {
            float pmax = redmax(lmax);          // uniform within lr-group
            float mnew = fmaxf(mrow, pmax);
            float al = __builtin_exp2f(mrow - mnew);
            lsum *= al;                          // per-lane partial, uniform scale
            #pragma unroll
            for (int r = 0; r < 4; ++r) {
                float ar = __shfl(al, lh * 20 + r, 64);
                o[0][r] *= ar; o[1][r] *= ar; o[2][r] *= ar; o[3][r] *= ar;
            }
            mrow = mnew;
        }
        float rsum = 0.f;
        uint pk[8];
        #pragma unroll
        for (int nt = 0; nt < 4; ++nt) {
            float p0 = __builtin_exp2f(s[nt][0] - mrow);
            float p1 = __builtin_exp2f(s[nt][1] - mrow);
            float p2 = __builtin_exp2f(s[nt][2] - mrow);
            float p3 = __builtin_exp2f(s[nt][3] - mrow);
            rsum += (p0 + p1) + (p2 + p3);
            pk[nt * 2]     = packbf(p0, p1);
            pk[nt * 2 + 1] = packbf(p2, p3);
        }
        lsum += rsum;                            // NO cross-lane reduce here
        uint4 w0 = {pk[0], pk[1], pk[2], pk[3]};
        uint4 w1 = {pk[4], pk[5], pk[6], pk[7]};
        bf16x8 pf0 = __builtin_bit_cast(bf16x8, w0);
        bf16x8 pf1 = __builtin_bit_cast(bf16x8, w1);
        __builtin_amdgcn_s_setprio(1);
        #pragma unroll
        for (int dt = 0; dt < 4; ++dt) {
            const char* vrow = V0 + (dt * 16 + lr) * 128;
            bf16x8 v0 = *(const bf16x8*)(vrow + off0);
            bf16x8 v1 = *(const bf16x8*)(vrow + off1);
            o[dt] = __builtin_amdgcn_mfma_f32_16x16x32_bf16(pf0, v0, o[dt], 0, 0, 0);
            o[dt] = __builtin_amdgcn_mfma_f32_16x16x32_bf16(pf1, v1, o[dt], 0, 0, 0);
        }
        __builtin_amdgcn_s_setprio(0);
    };

    #pragma unroll
    for (int i = 0; i < 2; ++i) {
        int j = i * 4 + wv;
        gload_lds16(kbase + (size_t)(j * 8 + srow) * D_ + scol, &sK[0][j * 512]);
        gload_lds16(vbase + (size_t)(j * 8 + srow) * T_ + scol, &sV[0][j * 512]);
    }
    __syncthreads();

    for (int kt = 0; kt <= qtB; ++kt) {
        const int cur = kt & 1;
        if (kt < qtB) {
            const int nb = cur ^ 1;
            #pragma unroll
            for (int i = 0; i < 2; ++i) {
                int j = i * 4 + wv;
                gload_lds16(kbase + (size_t)((kt + 1) * 64 + j * 8 + srow) * D_ + scol, &sK[nb][j * 512]);
                gload_lds16(vbase + (size_t)(j * 8 + srow) * T_ + (kt + 1) * 64 + scol, &sV[nb][j * 512]);
            }
        }
        const bool doA = kt <= qtA;
        const char* K0 = (const char*)sK[cur];
        const char* V0 = (const char*)sV[cur];

        f32x4 sa[4], sb[4];
        __builtin_amdgcn_s_setprio(1);
        #pragma unroll
        for (int nt = 0; nt < 4; ++nt) {
            const int kk  = ((lr >> 2) << 3) | (lr & 3) | ((nt & 1) << 2) | ((nt >> 1) << 5);
            const int swk = (kk & 7) << 4;
            const char* krow = K0 + kk * 128;
            bf16x8 k0 = *(const bf16x8*)(krow + ((16 * lh) ^ swk));
            bf16x8 k1 = *(const bf16x8*)(krow + ((64 + 16 * lh) ^ swk));
            f32x4 a = {0.f, 0.f, 0.f, 0.f};
            a = __builtin_amdgcn_mfma_f32_16x16x32_bf16(k0, qfB0, a, 0, 0, 0);
            a = __builtin_amdgcn_mfma_f32_16x16x32_bf16(k1, qfB1, a, 0, 0, 0);
            sb[nt] = a;
            if (doA) {
                f32x4 c = {0.f, 0.f, 0.f, 0.f};
                c = __builtin_amdgcn_mfma_f32_16x16x32_bf16(k0, qfA0, c, 0, 0, 0);
                c = __builtin_amdgcn_mfma_f32_16x16x32_bf16(k1, qfA1, c, 0, 0, 0);
                sa[nt] = c;
            }
        }
        __builtin_amdgcn_s_setprio(0);
        if (kt == qtB) maskS(sb);
        if (doA && kt == qtA) maskS(sa);

        softmax_pv(sb, mB, lB, oB, V0);
        if (doA) softmax_pv(sa, mA, lA, oA, V0);
        __syncthreads();
    }

    const int b = bh >> 4, h = bh & 15;
    auto writeout = [&](f32x4 (&o)[4], float lsum, int q0) {
        float inv = 1.f / redsum(lsum);          // single deferred cross-lane reduce
        #pragma unroll
        for (int r = 0; r < 4; ++r) {
            float ir = __shfl(inv, lh * 20 + r, 64);
            int q = q0 + lh * 4 + r;
            #pragma unroll
            for (int dt = 0; dt < 4; ++dt)
                ob[((size_t)b * T_ + q) * C_ + h * 64 + dt * 16 + lr] = f2bf(o[dt][r] * ir);
        }
    };
    writeout(oA, lA, qtA * 64 + wv * 16);
    writeout(oB, lB, qtB * 64 + wv * 16);
}

extern "C" void kernel_launch(void* const* d_in, const int* in_sizes, int n_in,
                              void* d_out, int out_size, void* d_ws, size_t ws_size,
                              hipStream_t stream) {
    const float* x     = (const float*)d_in[0];
    const float* w_qkv = (const float*)d_in[1];
    const float* b_qkv = (const float*)d_in[2];
    const float* w_out = (const float*)d_in[3];
    const float* b_out = (const float*)d_in[4];
    float* out = (float*)d_out;

    char* ws = (char*)d_ws;
    ushort* xb     = (ushort*)(ws + 0);           // 16 MB (aliased: attn out reuses after GEMM1)
    ushort* wqkvT  = (ushort*)(ws + 16777216);    // 6 MB
    ushort* woutT  = (ushort*)(ws + 23068672);    // 2 MB
    ushort* qkv    = (ushort*)(ws + 25165824);    // q,k (bh,t,d); v-third unused
    ushort* vT     = (ushort*)(ws + 75497472);    // 16 MB (bh,d,t), written by gemm_hk qkv
    ushort* attn   = xb;
    ushort* qb = qkv;
    ushort* kb = qkv + (size_t)BH_ * T_ * D_;

    prep_kernel<<<8192 + 3072 + 1024, 256, 0, stream>>>(x, xb, w_qkv, wqkvT, w_out, woutT);
    // persistent-n qkv: 8 x 32 = 256 blocks = exactly 1.0 dispatch wave, NG=3
    gemm_hk<8, 2, 3, true><<<dim3(8, B_ * T_ / 256), 512, 0, stream>>>(xb, wqkvT, b_qkv, qkv, vT);
    flash_kernel<<<BH_ * 16, 256, 0, stream>>>(qb, kb, vT, attn);
    // BM=256, BN=128: 8 x 32 = 256 blocks = exactly 1.0 wave, NG=1
    gemm_hk<8, 2, 1, false><<<dim3(C_ / 128, B_ * T_ / 256), 512, 0, stream>>>(attn, woutT, b_out, out, nullptr);
}